// Round 4
// baseline (439.128 us; speedup 1.0000x reference)
//
#include <hip/hip_runtime.h>

// 3x3 VALID cross-correlation (XLA conv: no kernel flip) + bias.
// x: 8192x8192 fp32, w: 3x3, bias scalar -> out: 8190x8190 fp32.
//
// Memory-bound: ideal traffic = 288 MiB read (1.08x amp) + 256 MiB write
// -> ~90us floor at 6.3 TB/s. Bench dur_us includes ~295us of fixed harness
// restore/poison work (conv dispatch itself is <165us per rocprof R1/R2).
//
// R3 -> R4: fix compile error — __builtin_nontemporal_load/store require
// clang ext_vector_type, not HIP's class-based float4/float2. Same plan as
// R3: RPT=24, non-temporal load/store on the single-use streams.

#define IH 8192
#define IW 8192
#define OH 8190
#define OW 8190
#define RPT 24   // output rows per thread

// Clang vector types (accepted by nontemporal builtins).
typedef float vf4 __attribute__((ext_vector_type(4)));               // 16B aligned
typedef float vf2 __attribute__((ext_vector_type(2)));               // 8B aligned
// Output row stride 8190 -> odd rows only 8B-aligned; alignment-4 store type.
typedef float vf4u __attribute__((ext_vector_type(4), aligned(4)));

__global__ __launch_bounds__(256) void conv2d_3x3_kernel(
    const float* __restrict__ x,
    const float* __restrict__ w,
    const float* __restrict__ bias,
    float* __restrict__ out)
{
    const int c0 = 4 * (blockIdx.x * 256 + threadIdx.x);  // 0..8188, mult of 4
    const int r0 = blockIdx.y * RPT;
    const bool tail = (c0 + 6 > IW);  // only the single lane with c0 == 8188

    const float w00 = w[0], w01 = w[1], w02 = w[2];
    const float w10 = w[3], w11 = w[4], w12 = w[5];
    const float w20 = w[6], w21 = w[7], w22 = w[8];
    const float bv = bias[0];

    float acc[RPT][4];
#pragma unroll
    for (int d = 0; d < RPT; ++d)
#pragma unroll
        for (int j = 0; j < 4; ++j) acc[d][j] = 0.0f;

    // Branchless tail handling: the float2 companion load sits at +4 floats
    // normally; for the tail lane shift it to -2 (in-bounds, 8B aligned) and
    // zero-select the values (they only feed masked output columns).
    const int g_off = tail ? -2 : 4;

    // Stream input rows r0 .. r0+RPT+1 (constant trip count -> full unroll).
    // Row index clamped to IH-1: clamped rows only contribute to output rows
    // >= OH, which are masked at store.
#pragma unroll
    for (int d = 0; d < RPT + 2; ++d) {
        int i = r0 + d;
        i = (i < IH) ? i : (IH - 1);
        const float* rp = x + (size_t)i * IW + c0;

        const vf4 f = __builtin_nontemporal_load((const vf4*)rp);
        const vf2 g = __builtin_nontemporal_load((const vf2*)(rp + g_off));

        float vv[6];
        vv[0] = f.x; vv[1] = f.y; vv[2] = f.z; vv[3] = f.w;
        vv[4] = tail ? 0.0f : g.x;
        vv[5] = tail ? 0.0f : g.y;

        // Input row d contributes: kernel row 0 -> out row d,
        // kernel row 1 -> out row d-1, kernel row 2 -> out row d-2.
        if (d < RPT) {
#pragma unroll
            for (int j = 0; j < 4; ++j)
                acc[d][j] += w00 * vv[j] + w01 * vv[j + 1] + w02 * vv[j + 2];
        }
        if (d >= 1 && d - 1 < RPT) {
#pragma unroll
            for (int j = 0; j < 4; ++j)
                acc[d - 1][j] += w10 * vv[j] + w11 * vv[j + 1] + w12 * vv[j + 2];
        }
        if (d >= 2) {
#pragma unroll
            for (int j = 0; j < 4; ++j)
                acc[d - 2][j] += w20 * vv[j] + w21 * vv[j + 1] + w22 * vv[j + 2];
        }
    }

#pragma unroll
    for (int d = 0; d < RPT; ++d) {
        const int r = r0 + d;
        if (r < OH) {  // wave-uniform (r depends only on blockIdx.y)
            float* op = out + (size_t)r * OW + c0;
            const float o0 = acc[d][0] + bv;
            const float o1 = acc[d][1] + bv;
            const float o2 = acc[d][2] + bv;
            const float o3 = acc[d][3] + bv;
            if (!tail) {
                vf4u o;
                o.x = o0; o.y = o1; o.z = o2; o.w = o3;
                __builtin_nontemporal_store(o, (vf4u*)op);
            } else {
                // c0 == 8188: only cols 8188, 8189 are valid.
                __builtin_nontemporal_store(o0, op);
                __builtin_nontemporal_store(o1, op + 1);
            }
        }
    }
}

extern "C" void kernel_launch(void* const* d_in, const int* in_sizes, int n_in,
                              void* d_out, int out_size, void* d_ws, size_t ws_size,
                              hipStream_t stream) {
    const float* x = (const float*)d_in[0];
    const float* w = (const float*)d_in[1];
    const float* b = (const float*)d_in[2];
    float* out     = (float*)d_out;

    dim3 block(256, 1, 1);
    dim3 grid(IW / 4 / 256,               // 8 column-group blocks
              (OH + RPT - 1) / RPT, 1);   // 342 row blocks
    conv2d_3x3_kernel<<<grid, block, 0, stream>>>(x, w, b, out);
}